// Round 1
// baseline (5843.524 us; speedup 1.0000x reference)
//
#include <hip/hip_runtime.h>
#include <hip/hip_bf16.h>
#include <hip/hip_fp16.h>
#include <cmath>

typedef _Float16 f16;
typedef _Float16 f16x8 __attribute__((ext_vector_type(8)));
typedef float f32x4 __attribute__((ext_vector_type(4)));

constexpr int B = 128, T = 64, S = 80, H = 512, E = 512;
constexpr int BH = B * H;      // 65536
constexpr int G4 = 4 * H;      // 2048

#define LB256 __launch_bounds__(256)

// ---------------- setup kernels (run every call; ws is re-poisoned) ----------------

__global__ LB256 void prep_weights(
    const float* __restrict__ Wih0, const float* __restrict__ Whh0,
    const float* __restrict__ Wih1, const float* __restrict__ Whh1,
    const float* __restrict__ Wout, const float* __restrict__ Win,
    const float* __restrict__ bih0, const float* __restrict__ bhh0,
    const float* __restrict__ bih1, const float* __restrict__ bhh1,
    f16* __restrict__ WB0, f16* __restrict__ WB1, f16* __restrict__ WoutB,
    float* __restrict__ WinT, float* __restrict__ bsum0, float* __restrict__ bsum1)
{
    int stride = gridDim.x * blockDim.x;
    int idx = blockIdx.x * blockDim.x + threadIdx.x;
    // WB0[n][k]: k<1024 -> Wih0[n][k], else Whh0[n][k-1024]   (n in [0,2048), K=1536)
    for (int i = idx; i < G4 * 1536; i += stride) {
        int n = i / 1536, k = i - n * 1536;
        float v = (k < 1024) ? Wih0[n * 1024 + k] : Whh0[n * 512 + (k - 1024)];
        WB0[i] = (f16)v;
    }
    // WB1[n][k]: k<512 -> Wih1[n][k], else Whh1[n][k-512]     (K=1024)
    for (int i = idx; i < G4 * 1024; i += stride) {
        int n = i >> 10, k = i & 1023;
        float v = (k < 512) ? Wih1[n * 512 + k] : Whh1[n * 512 + (k - 512)];
        WB1[i] = (f16)v;
    }
    // WoutB[n][k] = W_out[n][k], n<512, k<1024 (already row-major over k)
    for (int i = idx; i < 512 * 1024; i += stride) WoutB[i] = (f16)Wout[i];
    // WinT[k][n] = W_in[n][k]  (fp32, attention q stays fp32)
    for (int i = idx; i < 512 * 512; i += stride) {
        int k = i >> 9, n = i & 511;
        WinT[i] = Win[n * 512 + k];
    }
    for (int i = idx; i < G4; i += stride) {
        bsum0[i] = bih0[i] + bhh0[i];
        bsum1[i] = bih1[i] + bhh1[i];
    }
}

__global__ LB256 void prep_emb(const int* __restrict__ tokens,
                               const float* __restrict__ embtab,
                               f16* __restrict__ embF16)
{
    int stride = gridDim.x * blockDim.x;
    for (int i = blockIdx.x * blockDim.x + threadIdx.x; i < T * B * E; i += stride) {
        int e = i & 511;
        int tb = i >> 9;                    // t*B + b
        int tok = tokens[tb];
        embF16[i] = (f16)embtab[(size_t)tok * E + e];
    }
}

__global__ LB256 void init_state(const float* __restrict__ h0, const float* __restrict__ c0,
                                 f16* __restrict__ hs0, f16* __restrict__ hs1,
                                 float* __restrict__ c0s, float* __restrict__ c1s,
                                 f16* __restrict__ xprev)
{
    int stride = gridDim.x * blockDim.x;
    for (int i = blockIdx.x * blockDim.x + threadIdx.x; i < BH; i += stride) {
        hs0[i] = (f16)h0[i];            // layer 0 state, parity 0
        hs1[i] = (f16)h0[BH + i];       // layer 1 state, parity 0
        c0s[i] = c0[i];
        c1s[i] = c0[BH + i];
        xprev[i] = (f16)0.f;            // input-feeding starts at zero
    }
}

__global__ LB256 void final_copy(const f16* __restrict__ h0f, const f16* __restrict__ h1f,
                                 const float* __restrict__ c0s, const float* __restrict__ c1s,
                                 float* __restrict__ out_hT, float* __restrict__ out_cT)
{
    int stride = gridDim.x * blockDim.x;
    for (int i = blockIdx.x * blockDim.x + threadIdx.x; i < BH; i += stride) {
        out_hT[i] = (float)h0f[i];
        out_hT[BH + i] = (float)h1f[i];
        out_cT[i] = c0s[i];
        out_cT[BH + i] = c1s[i];
    }
}

// ---------------- per-timestep kernels ----------------

// gates[b][g*512+n] = sum_k A[b][k] * WB[g*512+n][k] + bias; fused LSTM cell.
// A is segmented: k<512 -> p0, k<1024 -> p1, k<1536 -> p2 (each [128][512] f16).
// block: 256 thr = 4 waves (one per gate), tile 16b x 16n, all 4 gates.
// grid: (512/16=32 ntiles, 128/16=8 btiles)
__global__ LB256 void lstm_kernel(
    const f16* __restrict__ p0, const f16* __restrict__ p1, const f16* __restrict__ p2,
    const int K,
    const f16* __restrict__ WB, const float* __restrict__ bsum,
    float* __restrict__ cst, f16* __restrict__ hnew)
{
    const int lane = threadIdx.x & 63;
    const int gate = threadIdx.x >> 6;     // wave id = gate
    const int quad = lane >> 4;
    const int mrow = lane & 15;
    const int b = blockIdx.y * 16 + mrow;  // A row (M index)
    const int n = blockIdx.x * 16 + mrow;  // B row (N index within gate)

    f32x4 acc = {0.f, 0.f, 0.f, 0.f};
    const f16* wrow = WB + (size_t)(gate * 512 + n) * K;
    const int arow = b * 512;

    #pragma unroll 8
    for (int k0 = 0; k0 < K; k0 += 32) {
        int k = k0 + quad * 8;
        const f16* ap = (k < 512)  ? (p0 + arow + k)
                      : (k < 1024) ? (p1 + arow + (k - 512))
                                   : (p2 + arow + (k - 1024));
        f16x8 av = *(const f16x8*)ap;
        f16x8 wv = *(const f16x8*)(wrow + k);
        acc = __builtin_amdgcn_mfma_f32_16x16x32_f16(av, wv, acc, 0, 0, 0);
    }

    // stage gates in LDS so one thread sees i,f,g,o for its (b,n)
    __shared__ float gbuf[4][16][17];
    #pragma unroll
    for (int r = 0; r < 4; ++r) gbuf[gate][quad * 4 + r][mrow] = acc[r];
    __syncthreads();

    const int brow = threadIdx.x >> 4;     // 0..15
    const int ncol = threadIdx.x & 15;
    const int gb = blockIdx.y * 16 + brow;
    const int gn = blockIdx.x * 16 + ncol;
    float zi = gbuf[0][brow][ncol] + bsum[gn];
    float zf = gbuf[1][brow][ncol] + bsum[512 + gn];
    float zg = gbuf[2][brow][ncol] + bsum[1024 + gn];
    float zo = gbuf[3][brow][ncol] + bsum[1536 + gn];
    float ig = 1.f / (1.f + expf(-zi));
    float fg = 1.f / (1.f + expf(-zf));
    float og = 1.f / (1.f + expf(-zo));
    float gg = tanhf(zg);
    int idx = gb * 512 + gn;
    float c = fg * cst[idx] + ig * gg;
    cst[idx] = c;
    hnew[idx] = (f16)(og * tanhf(c));
}

// attention, one block per batch row b; fp32 chain for accuracy of attns output
__global__ LB256 void attn_kernel(
    const f16* __restrict__ h1, const float* __restrict__ WinT,
    const float* __restrict__ context, float* __restrict__ attns_out,
    f16* __restrict__ wctx)
{
    const int b = blockIdx.x;
    const int tid = threadIdx.x;
    const int lane = tid & 63;
    const int wave = tid >> 6;
    __shared__ float h1s[512];
    __shared__ float q[512];
    __shared__ float sc[80];
    __shared__ float smax, ssum;

    for (int i = tid; i < 512; i += 256) h1s[i] = (float)h1[b * 512 + i];
    __syncthreads();

    // q[n] = sum_k h1[k] * W_in[n][k]  (WinT is [k][n])
    {
        float a0 = 0.f, a1 = 0.f;
        #pragma unroll 4
        for (int k = 0; k < 512; ++k) {
            float hv = h1s[k];
            a0 += hv * WinT[k * 512 + tid];
            a1 += hv * WinT[k * 512 + 256 + tid];
        }
        q[tid] = a0;
        q[tid + 256] = a1;
    }
    __syncthreads();

    // scores[s] = context[b][s][:] . q   -- one wave per s, shuffle reduce
    const float* ctxb = context + (size_t)b * S * 512;
    for (int s = wave; s < S; s += 4) {
        const float* crow = ctxb + s * 512;
        float a = 0.f;
        #pragma unroll
        for (int k = lane; k < 512; k += 64) a += crow[k] * q[k];
        #pragma unroll
        for (int off = 32; off > 0; off >>= 1) a += __shfl_down(a, off);
        if (lane == 0) sc[s] = a;
    }
    __syncthreads();

    if (tid == 0) {
        float m = -1e30f;
        for (int s = 0; s < S; ++s) m = fmaxf(m, sc[s]);
        smax = m;
    }
    __syncthreads();
    if (tid < S) sc[tid] = expf(sc[tid] - smax);
    __syncthreads();
    if (tid == 0) {
        float su = 0.f;
        for (int s = 0; s < S; ++s) su += sc[s];
        ssum = 1.f / su;
    }
    __syncthreads();
    if (tid < S) {
        float a = sc[tid] * ssum;
        sc[tid] = a;
        attns_out[b * S + tid] = a;
    }
    __syncthreads();

    // wctx[h] = sum_s attn[s] * context[b][s][h]
    for (int h = tid; h < 512; h += 256) {
        float a = 0.f;
        #pragma unroll 8
        for (int s = 0; s < S; ++s) a += sc[s] * ctxb[s * 512 + h];
        wctx[b * 512 + h] = (f16)a;
    }
}

// out[b][n] = tanh( [wctx | h1][b][:] . W_out[n][:] ), write fp32 to d_out and f16 to xprev
// block 256 thr = 4 waves (2x2 of 16x16), tile 32b x 32n; grid (16 ntiles, 4 btiles)
__global__ LB256 void outgemm_kernel(
    const f16* __restrict__ wctx, const f16* __restrict__ h1,
    const f16* __restrict__ WoutB, float* __restrict__ outp,
    f16* __restrict__ xprev)
{
    const int lane = threadIdx.x & 63;
    const int wave = threadIdx.x >> 6;
    const int quad = lane >> 4;
    const int mrow = lane & 15;
    const int wb = wave >> 1, wn = wave & 1;
    const int b = blockIdx.y * 32 + wb * 16 + mrow;
    const int n = blockIdx.x * 32 + wn * 16 + mrow;

    f32x4 acc = {0.f, 0.f, 0.f, 0.f};
    const f16* wrow = WoutB + (size_t)n * 1024;
    const int arow = b * 512;
    #pragma unroll 8
    for (int k0 = 0; k0 < 1024; k0 += 32) {
        int k = k0 + quad * 8;
        const f16* ap = (k < 512) ? (wctx + arow + k) : (h1 + arow + (k - 512));
        f16x8 av = *(const f16x8*)ap;
        f16x8 wv = *(const f16x8*)(wrow + k);
        acc = __builtin_amdgcn_mfma_f32_16x16x32_f16(av, wv, acc, 0, 0, 0);
    }

    const int col = blockIdx.x * 32 + wn * 16 + (lane & 15);
    #pragma unroll
    for (int r = 0; r < 4; ++r) {
        int row = blockIdx.y * 32 + wb * 16 + quad * 4 + r;
        float v = tanhf(acc[r]);
        outp[row * 512 + col] = v;
        xprev[row * 512 + col] = (f16)v;
    }
}

// ---------------- host ----------------

extern "C" void kernel_launch(void* const* d_in, const int* in_sizes, int n_in,
                              void* d_out, int out_size, void* d_ws, size_t ws_size,
                              hipStream_t stream)
{
    const int*   tokens  = (const int*)  d_in[0];
    const float* h0      = (const float*)d_in[1];
    const float* c0      = (const float*)d_in[2];
    const float* context = (const float*)d_in[3];
    const float* embtab  = (const float*)d_in[4];
    const float* Wih0    = (const float*)d_in[5];
    const float* Whh0    = (const float*)d_in[6];
    const float* bih0    = (const float*)d_in[7];
    const float* bhh0    = (const float*)d_in[8];
    const float* Wih1    = (const float*)d_in[9];
    const float* Whh1    = (const float*)d_in[10];
    const float* bih1    = (const float*)d_in[11];
    const float* bhh1    = (const float*)d_in[12];
    const float* Win     = (const float*)d_in[13];
    const float* Wout    = (const float*)d_in[14];

    float* outF        = (float*)d_out;
    float* out_outputs = outF;                          // [T][B][H]
    float* out_hT      = outF + (size_t)T * BH;         // [2][B][H]
    float* out_cT      = out_hT + 2 * BH;               // [2][B][H]
    float* out_attn    = out_cT + 2 * BH;               // [T][B][S]

    char* w = (char*)d_ws;
    auto alloc = [&](size_t bytes) {
        char* p = w;
        w += (bytes + 255) & ~(size_t)255;
        return p;
    };
    f16*   WB0    = (f16*)  alloc((size_t)G4 * 1536 * sizeof(f16));
    f16*   WB1    = (f16*)  alloc((size_t)G4 * 1024 * sizeof(f16));
    f16*   WoutB  = (f16*)  alloc((size_t)512 * 1024 * sizeof(f16));
    float* WinT   = (float*)alloc((size_t)512 * 512 * sizeof(float));
    float* bsum0  = (float*)alloc(G4 * sizeof(float));
    float* bsum1  = (float*)alloc(G4 * sizeof(float));
    f16*   embF16 = (f16*)  alloc((size_t)T * B * E * sizeof(f16));
    f16*   hs0    = (f16*)  alloc((size_t)2 * BH * sizeof(f16));   // parity ping-pong
    f16*   hs1    = (f16*)  alloc((size_t)2 * BH * sizeof(f16));
    float* c0s    = (float*)alloc((size_t)BH * sizeof(float));
    float* c1s    = (float*)alloc((size_t)BH * sizeof(float));
    f16*   xprev  = (f16*)  alloc((size_t)BH * sizeof(f16));
    f16*   wctxb  = (f16*)  alloc((size_t)BH * sizeof(f16));

    prep_weights<<<1024, 256, 0, stream>>>(Wih0, Whh0, Wih1, Whh1, Wout, Win,
                                           bih0, bhh0, bih1, bhh1,
                                           WB0, WB1, WoutB, WinT, bsum0, bsum1);
    prep_emb<<<2048, 256, 0, stream>>>(tokens, embtab, embF16);
    init_state<<<256, 256, 0, stream>>>(h0, c0, hs0, hs1, c0s, c1s, xprev);

    for (int t = 0; t < T; ++t) {
        const f16* h0old = hs0 + (t & 1) * BH;
        f16*       h0new = hs0 + ((t + 1) & 1) * BH;
        const f16* h1old = hs1 + (t & 1) * BH;
        f16*       h1new = hs1 + ((t + 1) & 1) * BH;
        const f16* embt  = embF16 + (size_t)t * BH;

        lstm_kernel<<<dim3(32, 8), 256, 0, stream>>>(
            embt, xprev, h0old, 1536, WB0, bsum0, c0s, h0new);
        lstm_kernel<<<dim3(32, 8), 256, 0, stream>>>(
            h0new, h1old, h1old, 1024, WB1, bsum1, c1s, h1new);
        attn_kernel<<<128, 256, 0, stream>>>(
            h1new, WinT, context, out_attn + (size_t)t * B * S, wctxb);
        outgemm_kernel<<<dim3(16, 4), 256, 0, stream>>>(
            wctxb, h1new, WoutB, out_outputs + (size_t)t * BH, xprev);
    }

    final_copy<<<256, 256, 0, stream>>>(hs0, hs1, c0s, c1s, out_hT, out_cT);
}